// Round 3
// baseline (466.869 us; speedup 1.0000x reference)
//
#include <hip/hip_runtime.h>
#include <hip/hip_bf16.h>

#define L_SEQ 2048
#define DM 512
#define NH 8
#define DH 64
#define NB 4

typedef __attribute__((ext_vector_type(4))) float f32x4;
typedef __attribute__((ext_vector_type(8))) short bf16x8;
typedef __attribute__((ext_vector_type(4))) unsigned short u16x4;
typedef __attribute__((ext_vector_type(4))) int i32x4;
typedef unsigned long long u64;

__device__ __forceinline__ unsigned short f2bf(float f) {
  __hip_bfloat16 h = __float2bfloat16(f);
  union { __hip_bfloat16 h; unsigned short u; } cv; cv.h = h; return cv.u;
}

__device__ __forceinline__ float fexp2(float x) {
#if __has_builtin(__builtin_amdgcn_exp2f)
  return __builtin_amdgcn_exp2f(x);
#else
  return __expf(x * 0.6931471805599453f);
#endif
}

#define SCL2 (0.044194173824159216f * 1.4426950408889634f)  // 1/sqrt(512)*log2(e)

// ---------------- mask -> bitmask (1 bit per element, 64 j's per u64) -------
__global__ void pack_mask_k(const int* __restrict__ mask, u64* __restrict__ bits,
                            int nwords) {
  int lane = threadIdx.x & 63;
  int w0 = (blockIdx.x * blockDim.x + threadIdx.x) >> 6;
  int stride = (gridDim.x * blockDim.x) >> 6;
  for (int w = w0; w < nwords; w += stride) {
    int m = mask[(size_t)w * 64 + lane];
    u64 b = __ballot(m != 0);
    if (lane == 0) bits[w] = b;
  }
}

// ---------------- GEMM: C[token, feat] = X @ W^T + bias ---------------------
template<int MODE>
__global__ __launch_bounds__(256, 3)
void gemm_k(const void* __restrict__ A0, const void* __restrict__ A1,
            const void* __restrict__ A2, const float* __restrict__ Bw,
            const float* __restrict__ bias,
            void* __restrict__ O0, void* __restrict__ O1, void* __restrict__ O2) {
  __shared__ __align__(16) unsigned short As[128 * 64];
  __shared__ __align__(16) unsigned short Bs[128 * 64];
  const int tid = threadIdx.x;
  const int lane = tid & 63;
  const int wv = tid >> 6, wr = wv >> 1, wc = wv & 1;
  const int c = lane & 15, g = lane >> 4;
  const int m0 = blockIdx.x * 128, n0 = blockIdx.y * 128;
  const int z = blockIdx.z;
  const void* Ap = (z == 0) ? A0 : (z == 1) ? A1 : A2;
  void* Op = (z == 0) ? O0 : (z == 1) ? O1 : O2;

  f32x4 acc[4][4] = {};

  for (int kit = 0; kit < 8; ++kit) {
    const int k0 = kit * 64;
    if (kit) __syncthreads();
    if constexpr (MODE == 1) {
      const unsigned short* A = (const unsigned short*)Ap;
      #pragma unroll
      for (int f = 0; f < 4; ++f) {
        int p = tid + f * 256;
        int row = p >> 3, ch = p & 7;
        i32x4 vdat = *(const i32x4*)(A + (size_t)(m0 + row) * DM + k0 + ch * 8);
        *(i32x4*)(As + row * 64 + ((ch ^ (row & 7)) * 8)) = vdat;
      }
    } else {
      const float* A = (const float*)Ap;
      #pragma unroll
      for (int f = 0; f < 8; ++f) {
        int p = tid + f * 256;
        int row = p >> 4, c4 = p & 15;
        f32x4 vv = *(const f32x4*)(A + (size_t)(m0 + row) * DM + k0 + c4 * 4);
        u16x4 hh = { f2bf(vv[0]), f2bf(vv[1]), f2bf(vv[2]), f2bf(vv[3]) };
        int ch = c4 >> 1, half = c4 & 1;
        *(u16x4*)(As + row * 64 + ((ch ^ (row & 7)) * 8) + half * 4) = hh;
      }
    }
    #pragma unroll
    for (int f = 0; f < 8; ++f) {
      int p = tid + f * 256;
      int row = p >> 4, c4 = p & 15;
      f32x4 vv = *(const f32x4*)(Bw + (size_t)(n0 + row) * DM + k0 + c4 * 4);
      u16x4 hh = { f2bf(vv[0]), f2bf(vv[1]), f2bf(vv[2]), f2bf(vv[3]) };
      int ch = c4 >> 1, half = c4 & 1;
      *(u16x4*)(Bs + row * 64 + ((ch ^ (row & 7)) * 8) + half * 4) = hh;
    }
    __syncthreads();
    #pragma unroll
    for (int ks = 0; ks < 2; ++ks) {
      bf16x8 av[4], bv_[4];
      #pragma unroll
      for (int m = 0; m < 4; ++m) {
        int row = wr * 64 + m * 16 + c;
        av[m] = *(const bf16x8*)(As + row * 64 + (((ks * 4 + g) ^ (row & 7)) * 8));
      }
      #pragma unroll
      for (int n = 0; n < 4; ++n) {
        int row = wc * 64 + n * 16 + c;
        bv_[n] = *(const bf16x8*)(Bs + row * 64 + (((ks * 4 + g) ^ (row & 7)) * 8));
      }
      __builtin_amdgcn_s_setprio(1);
      #pragma unroll
      for (int m = 0; m < 4; ++m)
        #pragma unroll
        for (int n = 0; n < 4; ++n)
          acc[m][n] = __builtin_amdgcn_mfma_f32_16x16x32_bf16(av[m], bv_[n], acc[m][n], 0, 0, 0);
      __builtin_amdgcn_s_setprio(0);
    }
  }

  float bvx[4];
  #pragma unroll
  for (int n = 0; n < 4; ++n) bvx[n] = bias[n0 + wc * 64 + n * 16 + c];

  if constexpr (MODE == 0) {
    unsigned short* O = (unsigned short*)Op;
    if (z < 2) {
      #pragma unroll
      for (int n = 0; n < 4; ++n) {
        int j = n0 + wc * 64 + n * 16 + c;
        int hd = j >> 6, d = j & 63;
        #pragma unroll
        for (int m = 0; m < 4; ++m) {
          int ib = m0 + wr * 64 + m * 16 + g * 4;
          int bb = ib >> 11, tok = ib & (L_SEQ - 1);
          size_t base = (((size_t)(bb * NH + hd)) * L_SEQ + tok) * DH + d;
          #pragma unroll
          for (int r = 0; r < 4; ++r)
            O[base + (size_t)r * DH] = f2bf(acc[m][n][r] + bvx[n]);
        }
      }
    } else {
      #pragma unroll
      for (int n = 0; n < 4; ++n) {
        int j = n0 + wc * 64 + n * 16 + c;
        int hd = j >> 6, d = j & 63;
        #pragma unroll
        for (int m = 0; m < 4; ++m) {
          int ib = m0 + wr * 64 + m * 16 + g * 4;
          int bb = ib >> 11, tok = ib & (L_SEQ - 1);
          u16x4 hh = { f2bf(acc[m][n][0] + bvx[n]), f2bf(acc[m][n][1] + bvx[n]),
                       f2bf(acc[m][n][2] + bvx[n]), f2bf(acc[m][n][3] + bvx[n]) };
          *(u16x4*)(O + (((size_t)(bb * NH + hd)) * DH + d) * L_SEQ + tok) = hh;
        }
      }
    }
  } else {
    float* O = (float*)Op;
    #pragma unroll
    for (int n = 0; n < 4; ++n) {
      int j = n0 + wc * 64 + n * 16 + c;
      #pragma unroll
      for (int m = 0; m < 4; ++m) {
        int ib = m0 + wr * 64 + m * 16 + g * 4;
        #pragma unroll
        for (int r = 0; r < 4; ++r)
          O[(size_t)(ib + r) * DM + j] = acc[m][n][r] + bvx[n];
      }
    }
  }
}

// ---------------- rowsum kernel ---------------------------------------------
// Each wave owns 16 q-rows (i = i0 + wv*16 + c) and sweeps ALL j.
// S^T = mfma(K, Q): lane (c,g) gets j = j0 + m*16 + g*4 + r, i = i0+wv*16+c.
// rs reduced over g lanes via shfl_xor(16/32). No LDS, no barriers.
__global__ __launch_bounds__(256, 4)
void rowsum_k(const unsigned short* __restrict__ qp,
              const unsigned short* __restrict__ kp,
              const u64* __restrict__ mbits,
              float* __restrict__ l2i) {
  const int tid = threadIdx.x, lane = tid & 63;
  const int wv = tid >> 6;
  const int c = lane & 15, g = lane >> 4;
  const int slot = blockIdx.x + blockIdx.y * gridDim.x;
  const int work = (slot & 7) * 128 + (slot >> 3);   // 1024 works, 128/XCD
  const int bh = work >> 5;
  const int i0 = (work & 31) * 64;
  const int b = bh >> 3;
  const unsigned short* qb = qp + (size_t)bh * L_SEQ * DH;
  const unsigned short* kb = kp + (size_t)bh * L_SEQ * DH;
  const int i = i0 + wv * 16 + c;
  const float NINF = -__builtin_inff();

  bf16x8 qf[2];
  #pragma unroll
  for (int k = 0; k < 2; ++k)
    qf[k] = *(const bf16x8*)(qb + (size_t)i * DH + k * 32 + g * 8);
  const int* mrow = (const int*)mbits + ((size_t)b * L_SEQ + i) * (L_SEQ / 32);

  float rs = 0.0f;
  for (int t = 0; t < 16; ++t) {
    const int j0 = t * 128;
    f32x4 acc[8] = {};
    #pragma unroll
    for (int k = 0; k < 2; ++k) {
      bf16x8 kf[8];
      #pragma unroll
      for (int m = 0; m < 8; ++m)
        kf[m] = *(const bf16x8*)(kb + (size_t)(j0 + m * 16 + c) * DH + k * 32 + g * 8);
      __builtin_amdgcn_s_setprio(1);
      #pragma unroll
      for (int m = 0; m < 8; ++m)
        acc[m] = __builtin_amdgcn_mfma_f32_16x16x32_bf16(kf[m], qf[k], acc[m], 0, 0, 0);
      __builtin_amdgcn_s_setprio(0);
    }
    i32x4 mw = *(const i32x4*)(mrow + (j0 >> 5));
    #pragma unroll
    for (int m = 0; m < 8; ++m) {
      unsigned bits4 = ((unsigned)mw[m >> 1] >> (((m & 1) * 16) + g * 4)) & 0xFu;
      #pragma unroll
      for (int r = 0; r < 4; ++r) {
        float arg = ((bits4 >> r) & 1) ? acc[m][r] * SCL2 : NINF;
        rs += fexp2(arg);
      }
    }
  }
  rs += __shfl_xor(rs, 16);
  rs += __shfl_xor(rs, 32);
  if (lane < 16)
    l2i[(size_t)bh * L_SEQ + i0 + wv * 16 + lane] = -__log2f(rs);
}

// ---------------- attention + PV (single sweep, wave-local, no barriers) ----
// E regroup acc->B-fragment in-register: j=g*4+r layout -> j=g*8+e layout via
// 2x ds_bpermute + cndmask per output word (T12-style lane-local PV operand).
__global__ __launch_bounds__(256, 3)
void attnpv_k(const unsigned short* __restrict__ qp,
              const unsigned short* __restrict__ kp,
              const unsigned short* __restrict__ vpT,
              const u64* __restrict__ mbits,
              const float* __restrict__ l2i,
              float* __restrict__ attn,
              unsigned short* __restrict__ ctx) {
  const int tid = threadIdx.x, lane = tid & 63;
  const int wv = tid >> 6;
  const int c = lane & 15, g = lane >> 4;
  const int slot = blockIdx.x + blockIdx.y * gridDim.x;
  const int work = (slot & 7) * 128 + (slot >> 3);
  const int bh = work >> 5;
  const int i0 = (work & 31) * 64;
  const int b = bh >> 3, hd = bh & 7;
  const unsigned short* qb = qp + (size_t)bh * L_SEQ * DH;
  const unsigned short* kb = kp + (size_t)bh * L_SEQ * DH;
  const unsigned short* vb = vpT + (size_t)bh * DH * L_SEQ;
  const int i = i0 + wv * 16 + c;
  float* arow = attn + (size_t)bh * L_SEQ * L_SEQ + (size_t)i * L_SEQ;
  const float NINF = -__builtin_inff();

  bf16x8 qf[2];
  #pragma unroll
  for (int k = 0; k < 2; ++k)
    qf[k] = *(const bf16x8*)(qb + (size_t)i * DH + k * 32 + g * 8);
  const float li = l2i[(size_t)bh * L_SEQ + i];
  const int* mrow = (const int*)mbits + ((size_t)b * L_SEQ + i) * (L_SEQ / 32);

  // bpermute index vectors: src lane = c + 16*((2g + b) & 3), in bytes
  const int idxA = 4 * (c + 16 * ((2 * g + 0) & 3));
  const int idxB = 4 * (c + 16 * ((2 * g + 1) & 3));
  const bool ghi = (g >= 2);

  f32x4 acc2[4] = {};   // ctx^T: d = dp*16 + g*4 + r, i = c-col

  for (int t = 0; t < 16; ++t) {
    const int j0 = t * 128;
    // ---- QK^T ----
    f32x4 acc[8] = {};
    #pragma unroll
    for (int k = 0; k < 2; ++k) {
      bf16x8 kf[8];
      #pragma unroll
      for (int m = 0; m < 8; ++m)
        kf[m] = *(const bf16x8*)(kb + (size_t)(j0 + m * 16 + c) * DH + k * 32 + g * 8);
      __builtin_amdgcn_s_setprio(1);
      #pragma unroll
      for (int m = 0; m < 8; ++m)
        acc[m] = __builtin_amdgcn_mfma_f32_16x16x32_bf16(kf[m], qf[k], acc[m], 0, 0, 0);
      __builtin_amdgcn_s_setprio(0);
    }
    // ---- E: normalized exp, attn store, pack bf16 pairs ----
    i32x4 mw = *(const i32x4*)(mrow + (j0 >> 5));
    int pk[8][2];
    #pragma unroll
    for (int m = 0; m < 8; ++m) {
      unsigned bits4 = ((unsigned)mw[m >> 1] >> (((m & 1) * 16) + g * 4)) & 0xFu;
      f32x4 fe;
      #pragma unroll
      for (int r = 0; r < 4; ++r) {
        float arg = ((bits4 >> r) & 1) ? fmaf(acc[m][r], SCL2, li) : NINF;
        fe[r] = fexp2(arg);
      }
      __builtin_nontemporal_store(fe, (f32x4*)(arow + j0 + m * 16 + g * 4));
      pk[m][0] = (int)f2bf(fe[0]) | ((int)f2bf(fe[1]) << 16);
      pk[m][1] = (int)f2bf(fe[2]) | ((int)f2bf(fe[3]) << 16);
    }
    // ---- V fragments (all d, all j-chunks of this tile) ----
    bf16x8 vf[4][4];
    #pragma unroll
    for (int ks = 0; ks < 4; ++ks)
      #pragma unroll
      for (int dp = 0; dp < 4; ++dp)
        vf[ks][dp] = *(const bf16x8*)(vb + (size_t)(dp * 16 + c) * L_SEQ + j0 + ks * 32 + g * 8);
    // ---- PV: regroup E in-register, then mfma(V^T, E) ----
    #pragma unroll
    for (int ks = 0; ks < 4; ++ks) {
      int ew[4];
      #pragma unroll
      for (int q = 0; q < 4; ++q) {
        int idx = (q < 2) ? idxA : idxB;
        int va = __builtin_amdgcn_ds_bpermute(idx, pk[2 * ks][q & 1]);
        int vb2 = __builtin_amdgcn_ds_bpermute(idx, pk[2 * ks + 1][q & 1]);
        ew[q] = ghi ? vb2 : va;
      }
      union { i32x4 w; bf16x8 h; } ef;
      ef.w = (i32x4){ew[0], ew[1], ew[2], ew[3]};
      __builtin_amdgcn_s_setprio(1);
      #pragma unroll
      for (int dp = 0; dp < 4; ++dp)
        acc2[dp] = __builtin_amdgcn_mfma_f32_16x16x32_bf16(vf[ks][dp], ef.h, acc2[dp], 0, 0, 0);
      __builtin_amdgcn_s_setprio(0);
    }
  }
  // ---- ctx write: lane (c,g): i fixed, d = dp*16 + g*4 + r ----
  size_t cbase = ((size_t)b * L_SEQ + i) * DM + hd * 64;
  #pragma unroll
  for (int dp = 0; dp < 4; ++dp) {
    u16x4 hh = { f2bf(acc2[dp][0]), f2bf(acc2[dp][1]),
                 f2bf(acc2[dp][2]), f2bf(acc2[dp][3]) };
    *(u16x4*)(ctx + cbase + dp * 16 + g * 4) = hh;
  }
}

// ---------------- launch ----------------------------------------------------
extern "C" void kernel_launch(void* const* d_in, const int* in_sizes, int n_in,
                              void* d_out, int out_size, void* d_ws, size_t ws_size,
                              hipStream_t stream) {
  const float* q    = (const float*)d_in[0];
  const float* k    = (const float*)d_in[1];
  const float* v    = (const float*)d_in[2];
  const int*   mask = (const int*)d_in[3];
  const float* wq   = (const float*)d_in[4];
  const float* bq   = (const float*)d_in[5];
  const float* wo   = (const float*)d_in[6];
  const float* bo   = (const float*)d_in[7];

  float* out  = (float*)d_out;
  float* attn = out + (size_t)NB * L_SEQ * DM;

  const size_t HEAD_ELEMS = (size_t)NB * NH * L_SEQ * DH;   // 4,194,304
  unsigned short* qp  = (unsigned short*)d_ws;
  unsigned short* kpb = qp + HEAD_ELEMS;
  unsigned short* vpT = kpb + HEAD_ELEMS;
  unsigned short* ctx = vpT + HEAD_ELEMS;
  u64* mbits = (u64*)(ctx + (size_t)NB * L_SEQ * DM);
  float* l2i = (float*)(mbits + (size_t)NB * L_SEQ * (L_SEQ / 64));

  pack_mask_k<<<2048, 256, 0, stream>>>(mask, mbits, NB * L_SEQ * (L_SEQ / 64));

  dim3 gproj(64, 4, 3);
  gemm_k<0><<<gproj, 256, 0, stream>>>(q, k, v, wq, bq, qp, kpb, vpT);

  rowsum_k<<<dim3(32, 32), 256, 0, stream>>>(qp, kpb, mbits, l2i);

  attnpv_k<<<dim3(32, 32), 256, 0, stream>>>(qp, kpb, vpT, mbits, l2i, attn, ctx);

  dim3 gout(64, 4, 1);
  gemm_k<1><<<gout, 256, 0, stream>>>(ctx, nullptr, nullptr, wo, bo, out, nullptr, nullptr);
}

// Round 4
// 453.179 us; speedup vs baseline: 1.0302x; 1.0302x over previous
//
#include <hip/hip_runtime.h>
#include <hip/hip_bf16.h>

#define L_SEQ 2048
#define DM 512
#define NH 8
#define DH 64
#define NB 4

typedef __attribute__((ext_vector_type(4))) float f32x4;
typedef __attribute__((ext_vector_type(8))) short bf16x8;
typedef __attribute__((ext_vector_type(4))) unsigned short u16x4;
typedef __attribute__((ext_vector_type(4))) int i32x4;
typedef __attribute__((ext_vector_type(2))) int i32x2;
typedef unsigned long long u64;

__device__ __forceinline__ unsigned short f2bf(float f) {
  __hip_bfloat16 h = __float2bfloat16(f);
  union { __hip_bfloat16 h; unsigned short u; } cv; cv.h = h; return cv.u;
}

__device__ __forceinline__ float fexp2(float x) {
#if __has_builtin(__builtin_amdgcn_exp2f)
  return __builtin_amdgcn_exp2f(x);
#else
  return __expf(x * 0.6931471805599453f);
#endif
}

#define SCL2 (0.044194173824159216f * 1.4426950408889634f)  // 1/sqrt(512)*log2(e)

// ---------------- mask -> bitmask (1 bit per element, 64 j's per u64) -------
__global__ void pack_mask_k(const int* __restrict__ mask, u64* __restrict__ bits,
                            int nwords) {
  int lane = threadIdx.x & 63;
  int w0 = (blockIdx.x * blockDim.x + threadIdx.x) >> 6;
  int stride = (gridDim.x * blockDim.x) >> 6;
  for (int w = w0; w < nwords; w += stride) {
    int m = mask[(size_t)w * 64 + lane];
    u64 b = __ballot(m != 0);
    if (lane == 0) bits[w] = b;
  }
}

// ---------------- GEMM: C[token, feat] = X @ W^T + bias ---------------------
template<int MODE>
__global__ __launch_bounds__(256, 3)
void gemm_k(const void* __restrict__ A0, const void* __restrict__ A1,
            const void* __restrict__ A2, const float* __restrict__ Bw,
            const float* __restrict__ bias,
            void* __restrict__ O0, void* __restrict__ O1, void* __restrict__ O2) {
  __shared__ __align__(16) unsigned short As[128 * 64];
  __shared__ __align__(16) unsigned short Bs[128 * 64];
  const int tid = threadIdx.x;
  const int lane = tid & 63;
  const int wv = tid >> 6, wr = wv >> 1, wc = wv & 1;
  const int c = lane & 15, g = lane >> 4;
  const int m0 = blockIdx.x * 128, n0 = blockIdx.y * 128;
  const int z = blockIdx.z;
  const void* Ap = (z == 0) ? A0 : (z == 1) ? A1 : A2;
  void* Op = (z == 0) ? O0 : (z == 1) ? O1 : O2;

  f32x4 acc[4][4] = {};

  for (int kit = 0; kit < 8; ++kit) {
    const int k0 = kit * 64;
    if (kit) __syncthreads();
    if constexpr (MODE == 1) {
      const unsigned short* A = (const unsigned short*)Ap;
      #pragma unroll
      for (int f = 0; f < 4; ++f) {
        int p = tid + f * 256;
        int row = p >> 3, ch = p & 7;
        i32x4 vdat = *(const i32x4*)(A + (size_t)(m0 + row) * DM + k0 + ch * 8);
        *(i32x4*)(As + row * 64 + ((ch ^ (row & 7)) * 8)) = vdat;
      }
    } else {
      const float* A = (const float*)Ap;
      #pragma unroll
      for (int f = 0; f < 8; ++f) {
        int p = tid + f * 256;
        int row = p >> 4, c4 = p & 15;
        f32x4 vv = *(const f32x4*)(A + (size_t)(m0 + row) * DM + k0 + c4 * 4);
        u16x4 hh = { f2bf(vv[0]), f2bf(vv[1]), f2bf(vv[2]), f2bf(vv[3]) };
        int ch = c4 >> 1, half = c4 & 1;
        *(u16x4*)(As + row * 64 + ((ch ^ (row & 7)) * 8) + half * 4) = hh;
      }
    }
    #pragma unroll
    for (int f = 0; f < 8; ++f) {
      int p = tid + f * 256;
      int row = p >> 4, c4 = p & 15;
      f32x4 vv = *(const f32x4*)(Bw + (size_t)(n0 + row) * DM + k0 + c4 * 4);
      u16x4 hh = { f2bf(vv[0]), f2bf(vv[1]), f2bf(vv[2]), f2bf(vv[3]) };
      int ch = c4 >> 1, half = c4 & 1;
      *(u16x4*)(Bs + row * 64 + ((ch ^ (row & 7)) * 8) + half * 4) = hh;
    }
    __syncthreads();
    #pragma unroll
    for (int ks = 0; ks < 2; ++ks) {
      bf16x8 av[4], bv_[4];
      #pragma unroll
      for (int m = 0; m < 4; ++m) {
        int row = wr * 64 + m * 16 + c;
        av[m] = *(const bf16x8*)(As + row * 64 + (((ks * 4 + g) ^ (row & 7)) * 8));
      }
      #pragma unroll
      for (int n = 0; n < 4; ++n) {
        int row = wc * 64 + n * 16 + c;
        bv_[n] = *(const bf16x8*)(Bs + row * 64 + (((ks * 4 + g) ^ (row & 7)) * 8));
      }
      __builtin_amdgcn_s_setprio(1);
      #pragma unroll
      for (int m = 0; m < 4; ++m)
        #pragma unroll
        for (int n = 0; n < 4; ++n)
          acc[m][n] = __builtin_amdgcn_mfma_f32_16x16x32_bf16(av[m], bv_[n], acc[m][n], 0, 0, 0);
      __builtin_amdgcn_s_setprio(0);
    }
  }

  float bvx[4];
  #pragma unroll
  for (int n = 0; n < 4; ++n) bvx[n] = bias[n0 + wc * 64 + n * 16 + c];

  if constexpr (MODE == 0) {
    unsigned short* O = (unsigned short*)Op;
    if (z < 2) {
      #pragma unroll
      for (int n = 0; n < 4; ++n) {
        int j = n0 + wc * 64 + n * 16 + c;
        int hd = j >> 6, d = j & 63;
        #pragma unroll
        for (int m = 0; m < 4; ++m) {
          int ib = m0 + wr * 64 + m * 16 + g * 4;
          int bb = ib >> 11, tok = ib & (L_SEQ - 1);
          size_t base = (((size_t)(bb * NH + hd)) * L_SEQ + tok) * DH + d;
          #pragma unroll
          for (int r = 0; r < 4; ++r)
            O[base + (size_t)r * DH] = f2bf(acc[m][n][r] + bvx[n]);
        }
      }
    } else {
      #pragma unroll
      for (int n = 0; n < 4; ++n) {
        int j = n0 + wc * 64 + n * 16 + c;
        int hd = j >> 6, d = j & 63;
        #pragma unroll
        for (int m = 0; m < 4; ++m) {
          int ib = m0 + wr * 64 + m * 16 + g * 4;
          int bb = ib >> 11, tok = ib & (L_SEQ - 1);
          u16x4 hh = { f2bf(acc[m][n][0] + bvx[n]), f2bf(acc[m][n][1] + bvx[n]),
                       f2bf(acc[m][n][2] + bvx[n]), f2bf(acc[m][n][3] + bvx[n]) };
          *(u16x4*)(O + (((size_t)(bb * NH + hd)) * DH + d) * L_SEQ + tok) = hh;
        }
      }
    }
  } else {
    float* O = (float*)Op;
    #pragma unroll
    for (int n = 0; n < 4; ++n) {
      int j = n0 + wc * 64 + n * 16 + c;
      #pragma unroll
      for (int m = 0; m < 4; ++m) {
        int ib = m0 + wr * 64 + m * 16 + g * 4;
        #pragma unroll
        for (int r = 0; r < 4; ++r)
          O[(size_t)(ib + r) * DM + j] = acc[m][n][r] + bvx[n];
      }
    }
  }
}

// ---------------- fused attention: 2 sweeps, zero barriers ------------------
// Wave owns 16 i-rows x all j. Sweep 1: rowsum of masked exp (wave-local
// shfl reduce). Sweep 2: recompute S (bit-identical), store normalized attn
// f32, stage E bf16 in WAVE-PRIVATE swizzled LDS (parity dbuf, lgkmcnt-only
// sync), PV = mfma(vpT-frag, E-frag) accumulating ctx^T in registers.
__global__ __launch_bounds__(256, 3)
void attnpv_k(const unsigned short* __restrict__ qp,
              const unsigned short* __restrict__ kp,
              const unsigned short* __restrict__ vpT,
              const u64* __restrict__ mbits,
              float* __restrict__ attn,
              unsigned short* __restrict__ ctx) {
  __shared__ __align__(16) unsigned short Elds[4][2][16 * 128];  // 32 KB
  const int tid = threadIdx.x, lane = tid & 63;
  const int wv = tid >> 6;
  const int c = lane & 15, g = lane >> 4;
  // XCD swizzle: 1024 blocks -> 128 consecutive works per XCD (4 heads/XCD)
  const int slot = blockIdx.x;
  const int work = (slot & 7) * 128 + (slot >> 3);
  const int bh = work >> 5;
  const int i0 = (work & 31) * 64;
  const int b = bh >> 3, hd = bh & 7;
  const unsigned short* qb = qp + (size_t)bh * L_SEQ * DH;
  const unsigned short* kb = kp + (size_t)bh * L_SEQ * DH;
  const unsigned short* vb = vpT + (size_t)bh * DH * L_SEQ;
  const int i = i0 + wv * 16 + c;                  // this lane's q-row
  float* arow = attn + (size_t)bh * L_SEQ * L_SEQ + (size_t)i * L_SEQ;
  const float NINF = -__builtin_inff();
  char* myE0 = (char*)&Elds[wv][0][0];
  char* myE1 = (char*)&Elds[wv][1][0];

  bf16x8 qf[2];
  #pragma unroll
  for (int k = 0; k < 2; ++k)
    qf[k] = *(const bf16x8*)(qb + (size_t)i * DH + k * 32 + g * 8);
  const int* mrow = (const int*)mbits + ((size_t)b * L_SEQ + i) * (L_SEQ / 32);

  // ---- sweep 1: rowsums (no LDS, no barriers) ----
  float rs = 0.0f;
  for (int t = 0; t < 16; ++t) {
    const int j0 = t * 128;
    f32x4 acc[8] = {};
    #pragma unroll
    for (int k = 0; k < 2; ++k) {
      bf16x8 kf[4];
      #pragma unroll
      for (int half = 0; half < 2; ++half) {
        #pragma unroll
        for (int m = 0; m < 4; ++m)
          kf[m] = *(const bf16x8*)(kb + (size_t)(j0 + (half * 4 + m) * 16 + c) * DH + k * 32 + g * 8);
        __builtin_amdgcn_s_setprio(1);
        #pragma unroll
        for (int m = 0; m < 4; ++m)
          acc[half * 4 + m] = __builtin_amdgcn_mfma_f32_16x16x32_bf16(kf[m], qf[k], acc[half * 4 + m], 0, 0, 0);
        __builtin_amdgcn_s_setprio(0);
      }
    }
    i32x4 mw = *(const i32x4*)(mrow + (j0 >> 5));
    #pragma unroll
    for (int m = 0; m < 8; ++m) {
      unsigned bits4 = ((unsigned)mw[m >> 1] >> (((m & 1) * 16) + g * 4)) & 0xFu;
      #pragma unroll
      for (int r = 0; r < 4; ++r) {
        float arg = ((bits4 >> r) & 1) ? acc[m][r] * SCL2 : NINF;
        rs += fexp2(arg);
      }
    }
  }
  rs += __shfl_xor(rs, 16);
  rs += __shfl_xor(rs, 32);
  const float li = -__log2f(rs);

  // ---- sweep 2: recompute, store attn, wave-private PV ----
  f32x4 acc2[4] = {};   // ctx^T: i = c, d = dp*16 + g*4 + r
  for (int t = 0; t < 16; ++t) {
    const int j0 = t * 128;
    char* myE = (t & 1) ? myE1 : myE0;
    // QK^T (identical to sweep 1 -> bit-identical S)
    f32x4 acc[8] = {};
    #pragma unroll
    for (int k = 0; k < 2; ++k) {
      bf16x8 kf[4];
      #pragma unroll
      for (int half = 0; half < 2; ++half) {
        #pragma unroll
        for (int m = 0; m < 4; ++m)
          kf[m] = *(const bf16x8*)(kb + (size_t)(j0 + (half * 4 + m) * 16 + c) * DH + k * 32 + g * 8);
        __builtin_amdgcn_s_setprio(1);
        #pragma unroll
        for (int m = 0; m < 4; ++m)
          acc[half * 4 + m] = __builtin_amdgcn_mfma_f32_16x16x32_bf16(kf[m], qf[k], acc[half * 4 + m], 0, 0, 0);
        __builtin_amdgcn_s_setprio(0);
      }
    }
    // E phase: normalized exp, f32 attn store, bf16 pack -> private LDS
    i32x4 mw = *(const i32x4*)(mrow + (j0 >> 5));
    #pragma unroll
    for (int m = 0; m < 8; ++m) {
      unsigned bits4 = ((unsigned)mw[m >> 1] >> (((m & 1) * 16) + g * 4)) & 0xFu;
      f32x4 fe;
      #pragma unroll
      for (int r = 0; r < 4; ++r) {
        float arg = ((bits4 >> r) & 1) ? fmaf(acc[m][r], SCL2, li) : NINF;
        fe[r] = fexp2(arg);
      }
      __builtin_nontemporal_store(fe, (f32x4*)(arow + j0 + m * 16 + g * 4));
      i32x2 pw;
      pw[0] = (int)f2bf(fe[0]) | ((int)f2bf(fe[1]) << 16);
      pw[1] = (int)f2bf(fe[2]) | ((int)f2bf(fe[3]) << 16);
      // row c, j-local = m*16+g*4 : byte = c*256 + 32m + 8g, swizzle bit4^=(c&7)
      int byte = c * 256 + 32 * m + 8 * g;
      *(i32x2*)(myE + (byte ^ ((c & 7) << 4))) = pw;
    }
    asm volatile("s_waitcnt lgkmcnt(0)" ::: "memory");
    __builtin_amdgcn_sched_barrier(0);
    // PV: ef = E[c][32ks + g*8 + e], vf = vpT[dp*16+c][j0+32ks+g*8+e]
    #pragma unroll
    for (int ks = 0; ks < 4; ++ks) {
      int ebyte = c * 256 + 64 * ks + 16 * g;
      bf16x8 ef = *(const bf16x8*)(myE + (ebyte ^ ((c & 7) << 4)));
      bf16x8 vf[4];
      #pragma unroll
      for (int dp = 0; dp < 4; ++dp)
        vf[dp] = *(const bf16x8*)(vb + (size_t)(dp * 16 + c) * L_SEQ + j0 + ks * 32 + g * 8);
      __builtin_amdgcn_s_setprio(1);
      #pragma unroll
      for (int dp = 0; dp < 4; ++dp)
        acc2[dp] = __builtin_amdgcn_mfma_f32_16x16x32_bf16(vf[dp], ef, acc2[dp], 0, 0, 0);
      __builtin_amdgcn_s_setprio(0);
    }
  }
  // ---- ctx write: lane (c,g): i = i0+wv*16+c, d = dp*16 + g*4 + r ----
  size_t cbase = ((size_t)b * L_SEQ + i) * DM + hd * 64;
  #pragma unroll
  for (int dp = 0; dp < 4; ++dp) {
    u16x4 hh = { f2bf(acc2[dp][0]), f2bf(acc2[dp][1]),
                 f2bf(acc2[dp][2]), f2bf(acc2[dp][3]) };
    *(u16x4*)(ctx + cbase + dp * 16 + g * 4) = hh;
  }
}

// ---------------- launch ----------------------------------------------------
extern "C" void kernel_launch(void* const* d_in, const int* in_sizes, int n_in,
                              void* d_out, int out_size, void* d_ws, size_t ws_size,
                              hipStream_t stream) {
  const float* q    = (const float*)d_in[0];
  const float* k    = (const float*)d_in[1];
  const float* v    = (const float*)d_in[2];
  const int*   mask = (const int*)d_in[3];
  const float* wq   = (const float*)d_in[4];
  const float* bq   = (const float*)d_in[5];
  const float* wo   = (const float*)d_in[6];
  const float* bo   = (const float*)d_in[7];

  float* out  = (float*)d_out;
  float* attn = out + (size_t)NB * L_SEQ * DM;

  const size_t HEAD_ELEMS = (size_t)NB * NH * L_SEQ * DH;   // 4,194,304
  unsigned short* qp  = (unsigned short*)d_ws;
  unsigned short* kpb = qp + HEAD_ELEMS;
  unsigned short* vpT = kpb + HEAD_ELEMS;
  unsigned short* ctx = vpT + HEAD_ELEMS;
  u64* mbits = (u64*)(ctx + (size_t)NB * L_SEQ * DM);

  pack_mask_k<<<2048, 256, 0, stream>>>(mask, mbits, NB * L_SEQ * (L_SEQ / 64));

  dim3 gproj(64, 4, 3);
  gemm_k<0><<<gproj, 256, 0, stream>>>(q, k, v, wq, bq, qp, kpb, vpT);

  attnpv_k<<<1024, 256, 0, stream>>>(qp, kpb, vpT, mbits, attn, ctx);

  dim3 gout(64, 4, 1);
  gemm_k<1><<<gout, 256, 0, stream>>>(ctx, nullptr, nullptr, wo, bo, out, nullptr, nullptr);
}